// Round 2
// baseline (509.838 us; speedup 1.0000x reference)
//
#include <hip/hip_runtime.h>
#include <math.h>

// ---------------------------------------------------------------------------
// Deformable transformer layer, MI355X round-1: bf16 MFMA GEMMs (m97-style
// global_load_lds staging, 128x128 tile), wave-per-query deform sampling.
// B=2, Nq=8192, C=256, HEADS=8, dh=32, LEVELS=3, POINTS=4, MLP=4
// ---------------------------------------------------------------------------

typedef short short8 __attribute__((ext_vector_type(8)));
typedef short s16x4 __attribute__((ext_vector_type(4)));
typedef __bf16 bf16x8 __attribute__((ext_vector_type(8)));
typedef float f32x4 __attribute__((ext_vector_type(4)));

__device__ __forceinline__ short f2b(float f) {
  unsigned u = __builtin_bit_cast(unsigned, f);
  u += 0x7fffu + ((u >> 16) & 1u);   // RNE to bf16
  return (short)(u >> 16);
}
__device__ __forceinline__ float b2f(short s) {
  unsigned u = ((unsigned)(unsigned short)s) << 16;
  return __builtin_bit_cast(float, u);
}

__device__ __forceinline__ f32x4 mfma16(short8 a, short8 b, f32x4 c) {
  return __builtin_amdgcn_mfma_f32_16x16x32_bf16(
      __builtin_bit_cast(bf16x8, a), __builtin_bit_cast(bf16x8, b), c, 0, 0, 0);
}

typedef __attribute__((address_space(3))) unsigned int lds_u32;
typedef const __attribute__((address_space(1))) unsigned int glb_u32;
__device__ __forceinline__ void glds16(const void* g, void* l) {
  // per-lane global addr; LDS dest = uniform base + lane*16 (HW rule)
  __builtin_amdgcn_global_load_lds((glb_u32*)g, (lds_u32*)l, 16, 0, 0);
}

// ---------------------------------------------------------------------------
// Weight convert + transpose: Wt[n][k] bf16 from W[k][n] fp32 (zero-pad jobs).
// grid = (256, 7). 32x32 tiles via LDS.
// ---------------------------------------------------------------------------
__global__ __launch_bounds__(256) void wconvert(
    const float* __restrict__ Wo, const float* __restrict__ Wa,
    const float* __restrict__ Wv, const float* __restrict__ Wp,
    const float* __restrict__ Wf1, const float* __restrict__ Wf2,
    short* __restrict__ t_oa, short* __restrict__ t_v, short* __restrict__ t_p,
    short* __restrict__ t_f1, short* __restrict__ t_f2)
{
  __shared__ float tile[32][33];
  int K, N, noff; const float* src; short* dst;
  switch (blockIdx.y) {
    case 0: src = Wo;      dst = t_oa; K = 256;  N = 192;  noff = 0;   break;
    case 1: src = Wa;      dst = t_oa; K = 256;  N = 96;   noff = 192; break;
    case 2: src = nullptr; dst = t_oa; K = 256;  N = 96;   noff = 288; break;
    case 3: src = Wv;      dst = t_v;  K = 256;  N = 256;  noff = 0;   break;
    case 4: src = Wp;      dst = t_p;  K = 256;  N = 256;  noff = 0;   break;
    case 5: src = Wf1;     dst = t_f1; K = 256;  N = 1024; noff = 0;   break;
    default: src = Wf2;    dst = t_f2; K = 1024; N = 256;  noff = 0;   break;
  }
  const int tilesK = K >> 5;
  const int nt = tilesK * (N >> 5);
  if ((int)blockIdx.x >= nt) return;
  const int tk = blockIdx.x % tilesK, tn = blockIdx.x / tilesK;
  const int k0 = tk * 32, n0 = tn * 32;
  const int t = threadIdx.x;
  const int r = t >> 3, c4 = (t & 7) * 4;
  float4 v = make_float4(0.f, 0.f, 0.f, 0.f);
  if (src) v = *(const float4*)(src + (size_t)(k0 + r) * N + n0 + c4);
  tile[r][c4] = v.x; tile[r][c4 + 1] = v.y; tile[r][c4 + 2] = v.z; tile[r][c4 + 3] = v.w;
  __syncthreads();
  const int nn = t >> 3, kc = (t & 7) * 4;
  s16x4 o;
  o.x = f2b(tile[kc][nn]); o.y = f2b(tile[kc + 1][nn]);
  o.z = f2b(tile[kc + 2][nn]); o.w = f2b(tile[kc + 3][nn]);
  *(s16x4*)(dst + (size_t)(noff + n0 + nn) * K + k0 + kc) = o;
}

// ---------------------------------------------------------------------------
// value fp32 [12600x256] -> bf16 [12672x256] (zero-padded rows)
// ---------------------------------------------------------------------------
__global__ __launch_bounds__(256) void vconvert(const float* __restrict__ x,
                                                short* __restrict__ y)
{
  const int i = (blockIdx.x * 256 + threadIdx.x) * 4;
  if (i >= 12672 * 256) return;
  s16x4 o = (s16x4){0, 0, 0, 0};
  if (i < 12600 * 256) {
    float4 v = *(const float4*)(x + i);
    o.x = f2b(v.x); o.y = f2b(v.y); o.z = f2b(v.z); o.w = f2b(v.w);
  }
  *(s16x4*)(y + i) = o;
}

// ---------------------------------------------------------------------------
// LayerNorm: one wave per row of 256. yf (fp32, optional), ybf (bf16,
// optional) = normalized (+ pos if given).
// ---------------------------------------------------------------------------
__global__ __launch_bounds__(256) void ln_kernel(
    const float* __restrict__ x, const float* __restrict__ pos,
    const float* __restrict__ g, const float* __restrict__ bta,
    float* __restrict__ yf, short* __restrict__ ybf)
{
  const int row  = blockIdx.x * 4 + (threadIdx.x >> 6);
  const int lane = threadIdx.x & 63;
  const float4 v = ((const float4*)(x + (size_t)row * 256))[lane];
  float s = v.x + v.y + v.z + v.w;
#pragma unroll
  for (int o = 32; o; o >>= 1) s += __shfl_xor(s, o);
  const float mean = s * (1.f / 256.f);
  const float dx = v.x - mean, dy = v.y - mean, dz = v.z - mean, dw = v.w - mean;
  float s2 = dx * dx + dy * dy + dz * dz + dw * dw;
#pragma unroll
  for (int o = 32; o; o >>= 1) s2 += __shfl_xor(s2, o);
  const float inv = rsqrtf(s2 * (1.f / 256.f) + 1e-5f);
  const float4 gv = ((const float4*)g)[lane];
  const float4 bv = ((const float4*)bta)[lane];
  float4 o1 = make_float4(dx * inv * gv.x + bv.x, dy * inv * gv.y + bv.y,
                          dz * inv * gv.z + bv.z, dw * inv * gv.w + bv.w);
  if (yf) ((float4*)(yf + (size_t)row * 256))[lane] = o1;
  if (ybf) {
    if (pos) {
      const float4 pv = ((const float4*)(pos + (size_t)row * 256))[lane];
      o1.x += pv.x; o1.y += pv.y; o1.z += pv.z; o1.w += pv.w;
    }
    s16x4 ob; ob.x = f2b(o1.x); ob.y = f2b(o1.y); ob.z = f2b(o1.z); ob.w = f2b(o1.w);
    ((s16x4*)(ybf + (size_t)row * 256))[lane] = ob;
  }
}

// ---------------------------------------------------------------------------
// bf16 MFMA GEMM, m97 structure: C[M,Nreal] = A[Mpad,K]@Bt[Npad,K]^T + epi.
// 128x128 tile, BK=32, 4 waves, global_load_lds width-16 staging.
// EPI: 0=f32+bias | 1=gelu->bf16 | 2=f32+bias+add1+add2 | 3=f32+bias+add1
//      4=oa (bias split 192/96, f32) | 5=bf16+bias
// ---------------------------------------------------------------------------
template <int EPI>
__global__ __launch_bounds__(256) void gemm_bf16(
    const short* __restrict__ A, const short* __restrict__ Bt,
    const float* __restrict__ bias, const float* __restrict__ bias2,
    const float* __restrict__ add1, const float* __restrict__ add2,
    void* __restrict__ Cout, int M, int Nreal, int ldc, int K)
{
  __shared__ short lA[128 * 32];
  __shared__ short lB[128 * 32];
  const int t = threadIdx.x;
  const int wave = t >> 6, lane = t & 63;
  const int quad = lane >> 4, l16 = lane & 15;
  const int wm = (wave & 1) * 64, wn = (wave >> 1) * 64;
  const int m0 = blockIdx.y * 128, n0 = blockIdx.x * 128;

  f32x4 acc[4][4];
#pragma unroll
  for (int i = 0; i < 4; i++)
#pragma unroll
    for (int j = 0; j < 4; j++) acc[i][j] = (f32x4){0.f, 0.f, 0.f, 0.f};

  // staging: wave covers rows wave*32 .. +31 (two 16-row segments)
  const int srow = lane >> 2, skc = (lane & 3) * 8;
  const short* gA = A + (size_t)(m0 + wave * 32 + srow) * K + skc;
  const short* gB = Bt + (size_t)(n0 + wave * 32 + srow) * K + skc;
  short* lAw = lA + wave * 1024;  // bytes: wave*2048
  short* lBw = lB + wave * 1024;

  for (int k0 = 0; k0 < K; k0 += 32) {
    __syncthreads();  // previous tile's reads done
    glds16(gA + k0, lAw);
    glds16(gA + (size_t)16 * K + k0, lAw + 512);
    glds16(gB + k0, lBw);
    glds16(gB + (size_t)16 * K + k0, lBw + 512);
    __syncthreads();  // vmcnt(0) drain + barrier

    short8 af[4], bf[4];
#pragma unroll
    for (int i = 0; i < 4; i++) {
      af[i] = *(const short8*)&lA[(wm + i * 16 + l16) * 32 + quad * 8];
      bf[i] = *(const short8*)&lB[(wn + i * 16 + l16) * 32 + quad * 8];
    }
#pragma unroll
    for (int i = 0; i < 4; i++)
#pragma unroll
      for (int j = 0; j < 4; j++) acc[i][j] = mfma16(af[i], bf[j], acc[i][j]);
  }

#pragma unroll
  for (int j = 0; j < 4; j++) {
    const int gn = n0 + wn + j * 16 + l16;
    if (gn >= Nreal) continue;
    float bb;
    if (EPI == 4) bb = (gn < 192) ? bias[gn] : bias2[gn - 192];
    else bb = bias[gn];
#pragma unroll
    for (int i = 0; i < 4; i++) {
#pragma unroll
      for (int r = 0; r < 4; r++) {
        const int gm = m0 + wm + i * 16 + quad * 4 + r;
        if (gm >= M) continue;
        float val = acc[i][j][r] + bb;
        if (EPI == 1) {
          val = 0.5f * val * (1.f + erff(val * 0.70710678118654752f));
          ((short*)Cout)[(size_t)gm * ldc + gn] = f2b(val);
        } else if (EPI == 5) {
          ((short*)Cout)[(size_t)gm * ldc + gn] = f2b(val);
        } else {
          if (EPI == 2) val += add1[(size_t)gm * ldc + gn] + add2[(size_t)gm * ldc + gn];
          if (EPI == 3) val += add1[(size_t)gm * ldc + gn];
          ((float*)Cout)[(size_t)gm * ldc + gn] = val;
        }
      }
    }
  }
}

// ---------------------------------------------------------------------------
// Softmax over 12 logits per (b,q,h), in place; oa row stride 288, aw at 192.
// ---------------------------------------------------------------------------
__global__ __launch_bounds__(256) void softmax12(float* __restrict__ oa)
{
  const int g = blockIdx.x * 256 + threadIdx.x;  // 131072 groups
  float* p = oa + (size_t)(g >> 3) * 288 + 192 + (g & 7) * 12;
  float mx = p[0];
#pragma unroll
  for (int i = 1; i < 12; i++) mx = fmaxf(mx, p[i]);
  float e[12], sum = 0.f;
#pragma unroll
  for (int i = 0; i < 12; i++) { e[i] = __expf(p[i] - mx); sum += e[i]; }
  const float inv = 1.f / sum;
#pragma unroll
  for (int i = 0; i < 12; i++) p[i] = e[i] * inv;
}

// ---------------------------------------------------------------------------
// Deformable sampling: one wave per (b,q). lane = h*8 + c; lane covers
// channels 4c..4c+3 of head h via bf16x4 gathers. Output bf16.
// ---------------------------------------------------------------------------
__device__ __forceinline__ float4 vfetch4(const short* __restrict__ vl,
                                          int x, int y, int W, int H)
{
  if (x < 0 || x >= W || y < 0 || y >= H) return make_float4(0.f, 0.f, 0.f, 0.f);
  const s16x4 s = *(const s16x4*)(vl + (size_t)(y * W + x) * 256);
  return make_float4(b2f(s.x), b2f(s.y), b2f(s.z), b2f(s.w));
}

__global__ __launch_bounds__(256) void deform_sample(
    const short* __restrict__ vproj, const float* __restrict__ oa,
    const float* __restrict__ refp, short* __restrict__ out)
{
  const int row  = blockIdx.x * 4 + (threadIdx.x >> 6);  // b*8192+q
  const int lane = threadIdx.x & 63;
  const int h = lane >> 3, c = lane & 7;
  const float* oarow = oa + (size_t)row * 288;
  const float* offr  = oarow + h * 24;
  const float* awr   = oarow + 192 + h * 12;
  const float* rp    = refp + (size_t)row * 6;
  const int b = row >> 13;
  const short* vb = vproj + (size_t)b * 6300 * 256 + h * 32 + c * 4;

  const int Hs[3] = {60, 30, 15}, Ws[3] = {80, 40, 20}, St[3] = {0, 4800, 6000};
  float ax = 0.f, ay = 0.f, az = 0.f, aw4 = 0.f;
#pragma unroll
  for (int l = 0; l < 3; l++) {
    const float rx = rp[l * 2], ry = rp[l * 2 + 1];
    const int W = Ws[l], H = Hs[l];
    const short* vl = vb + (size_t)St[l] * 256;
#pragma unroll
    for (int p = 0; p < 4; p++) {
      const float gx = rx * W + offr[(l * 4 + p) * 2]     - 0.5f;
      const float gy = ry * H + offr[(l * 4 + p) * 2 + 1] - 0.5f;
      const float w  = awr[l * 4 + p];
      const float x0f = floorf(gx), y0f = floorf(gy);
      const float wx = gx - x0f, wy = gy - y0f;
      const int x0 = (int)x0f, y0 = (int)y0f;
      const float4 s00 = vfetch4(vl, x0,     y0,     W, H);
      const float4 s10 = vfetch4(vl, x0 + 1, y0,     W, H);
      const float4 s01 = vfetch4(vl, x0,     y0 + 1, W, H);
      const float4 s11 = vfetch4(vl, x0 + 1, y0 + 1, W, H);
      const float w00 = w * (1.f - wx) * (1.f - wy), w10 = w * wx * (1.f - wy);
      const float w01 = w * (1.f - wx) * wy,         w11 = w * wx * wy;
      ax += w00 * s00.x + w10 * s10.x + w01 * s01.x + w11 * s11.x;
      ay += w00 * s00.y + w10 * s10.y + w01 * s01.y + w11 * s11.y;
      az += w00 * s00.z + w10 * s10.z + w01 * s01.z + w11 * s11.z;
      aw4 += w00 * s00.w + w10 * s10.w + w01 * s01.w + w11 * s11.w;
    }
  }
  s16x4 o; o.x = f2b(ax); o.y = f2b(ay); o.z = f2b(az); o.w = f2b(aw4);
  *(s16x4*)(out + (size_t)row * 256 + h * 32 + c * 4) = o;
}

// ---------------------------------------------------------------------------
// Launch
// ---------------------------------------------------------------------------
extern "C" void kernel_launch(void* const* d_in, const int* in_sizes, int n_in,
                              void* d_out, int out_size, void* d_ws, size_t ws_size,
                              hipStream_t stream)
{
  const float* query     = (const float*)d_in[0];
  const float* value     = (const float*)d_in[1];
  const float* query_pos = (const float*)d_in[2];
  const float* ref_pts   = (const float*)d_in[3];
  const float* g1  = (const float*)d_in[6];
  const float* b1  = (const float*)d_in[7];
  const float* Wo  = (const float*)d_in[8];
  const float* bo  = (const float*)d_in[9];
  const float* Wa  = (const float*)d_in[10];
  const float* ba  = (const float*)d_in[11];
  const float* Wv  = (const float*)d_in[12];
  const float* bv  = (const float*)d_in[13];
  const float* Wp  = (const float*)d_in[14];
  const float* bp  = (const float*)d_in[15];
  const float* g2  = (const float*)d_in[16];
  const float* b2  = (const float*)d_in[17];
  const float* Wf1 = (const float*)d_in[18];
  const float* bf1 = (const float*)d_in[19];
  const float* Wf2 = (const float*)d_in[20];
  const float* bf2 = (const float*)d_in[21];

  char* ws = (char*)d_ws;
  // byte offsets (see lifetime plan); total 83.7 MB
  short* wt_oa   = (short*)(ws + 0);          // 384x256 bf16
  short* wt_v    = (short*)(ws + 196608);     // 256x256
  short* wt_p    = (short*)(ws + 327680);     // 256x256
  short* wt_f1   = (short*)(ws + 458752);     // 1024x256
  short* wt_f2   = (short*)(ws + 983040);     // 256x1024
  float* qn      = (float*)(ws + 1507328);    // 16384x256 f32
  short* qa      = (short*)(ws + 18284544);   // 16384x256 bf16 (later q2)
  float* oabuf   = (float*)(ws + 26673152);   // 16384x288 f32
  short* vproj   = (short*)(ws + 45547520);   // 12600x256 bf16
  short* sampled = (short*)(ws + 52035584);   // 16384x256 bf16
  float* qbuf    = (float*)(ws + 60424192);   // 16384x256 f32
  short* valbf   = (short*)(ws + 77201408);   // 12672x256 bf16 (padded)
  short* q2      = qa;                        // reuse (qa dead after oa GEMM)
  short* hidden  = (short*)(ws + 26673152);   // 16384x1024 bf16, reuses
                                              // oa+vproj+sampled (all dead)
  float* outp = (float*)d_out;

  // 0. weights -> bf16 transposed; value -> bf16 padded
  wconvert<<<dim3(256, 7), 256, 0, stream>>>(Wo, Wa, Wv, Wp, Wf1, Wf2,
                                             wt_oa, wt_v, wt_p, wt_f1, wt_f2);
  vconvert<<<3169, 256, 0, stream>>>(value, valbf);
  // 1. qn = LN(query) f32; qa = (qn + pos) bf16
  ln_kernel<<<4096, 256, 0, stream>>>(query, query_pos, g1, b1, qn, qa);
  // 2. oa = qa @ [Wo|Wa] + [bo|ba]   [16384 x 288] f32
  gemm_bf16<4><<<dim3(3, 128), 256, 0, stream>>>(qa, wt_oa, bo, ba, nullptr,
                                                 nullptr, oabuf, 16384, 288, 288, 256);
  // 3. softmax over 12 per (b,q,h)
  softmax12<<<512, 256, 0, stream>>>(oabuf);
  // 4. vproj = value @ Wv + bv -> bf16   [12600 x 256]
  gemm_bf16<5><<<dim3(2, 99), 256, 0, stream>>>(valbf, wt_v, bv, nullptr, nullptr,
                                                nullptr, vproj, 12600, 256, 256, 256);
  // 5. deformable sampling -> sampled bf16 [16384 x 256]
  deform_sample<<<4096, 256, 0, stream>>>(vproj, oabuf, ref_pts, sampled);
  // 6. qbuf = sampled @ Wp + bp + qn + query   f32
  gemm_bf16<2><<<dim3(2, 128), 256, 0, stream>>>(sampled, wt_p, bp, nullptr, qn,
                                                 (const float*)query, qbuf,
                                                 16384, 256, 256, 256);
  // 7. q2 = LN(qbuf) bf16
  ln_kernel<<<4096, 256, 0, stream>>>(qbuf, nullptr, g2, b2, nullptr, q2);
  // 8. hidden = gelu(q2 @ Wf1 + bf1) bf16   [16384 x 1024]
  gemm_bf16<1><<<dim3(8, 128), 256, 0, stream>>>(q2, wt_f1, bf1, nullptr, nullptr,
                                                 nullptr, hidden, 16384, 1024, 1024, 256);
  // 9. out = qbuf + hidden @ Wf2 + bf2   f32
  gemm_bf16<3><<<dim3(2, 128), 256, 0, stream>>>(hidden, wt_f2, bf2, nullptr, qbuf,
                                                 nullptr, outp, 16384, 256, 256, 1024);
}

// Round 3
// 360.292 us; speedup vs baseline: 1.4151x; 1.4151x over previous
//
#include <hip/hip_runtime.h>
#include <math.h>

// ---------------------------------------------------------------------------
// Deformable transformer layer, MI355X round-2: two-phase deform sampling
// (prep tables + lean gather), bf16 MFMA GEMMs (m97-style staging).
// B=2, Nq=8192, C=256, HEADS=8, dh=32, LEVELS=3, POINTS=4, MLP=4
// ---------------------------------------------------------------------------

typedef short short8 __attribute__((ext_vector_type(8)));
typedef short s16x4 __attribute__((ext_vector_type(4)));
typedef __bf16 bf16x8 __attribute__((ext_vector_type(8)));
typedef float f32x4 __attribute__((ext_vector_type(4)));

__device__ __forceinline__ short f2b(float f) {
  unsigned u = __builtin_bit_cast(unsigned, f);
  u += 0x7fffu + ((u >> 16) & 1u);   // RNE to bf16
  return (short)(u >> 16);
}
__device__ __forceinline__ float b2f(short s) {
  unsigned u = ((unsigned)(unsigned short)s) << 16;
  return __builtin_bit_cast(float, u);
}
__device__ __forceinline__ void b8f(short8 s, float* f) {
  const uint4 u = __builtin_bit_cast(uint4, s);
  f[0] = __builtin_bit_cast(float, u.x << 16);
  f[1] = __builtin_bit_cast(float, u.x & 0xffff0000u);
  f[2] = __builtin_bit_cast(float, u.y << 16);
  f[3] = __builtin_bit_cast(float, u.y & 0xffff0000u);
  f[4] = __builtin_bit_cast(float, u.z << 16);
  f[5] = __builtin_bit_cast(float, u.z & 0xffff0000u);
  f[6] = __builtin_bit_cast(float, u.w << 16);
  f[7] = __builtin_bit_cast(float, u.w & 0xffff0000u);
}

__device__ __forceinline__ f32x4 mfma16(short8 a, short8 b, f32x4 c) {
  return __builtin_amdgcn_mfma_f32_16x16x32_bf16(
      __builtin_bit_cast(bf16x8, a), __builtin_bit_cast(bf16x8, b), c, 0, 0, 0);
}

typedef __attribute__((address_space(3))) unsigned int lds_u32;
typedef const __attribute__((address_space(1))) unsigned int glb_u32;
__device__ __forceinline__ void glds16(const void* g, void* l) {
  __builtin_amdgcn_global_load_lds((glb_u32*)g, (lds_u32*)l, 16, 0, 0);
}

// ---------------------------------------------------------------------------
// Weight convert + transpose: Wt[n][k] bf16 from W[k][n] fp32.
// ---------------------------------------------------------------------------
__global__ __launch_bounds__(256) void wconvert(
    const float* __restrict__ Wo, const float* __restrict__ Wa,
    const float* __restrict__ Wv, const float* __restrict__ Wp,
    const float* __restrict__ Wf1, const float* __restrict__ Wf2,
    short* __restrict__ t_oa, short* __restrict__ t_v, short* __restrict__ t_p,
    short* __restrict__ t_f1, short* __restrict__ t_f2)
{
  __shared__ float tile[32][33];
  int K, N, noff; const float* src; short* dst;
  switch (blockIdx.y) {
    case 0: src = Wo;      dst = t_oa; K = 256;  N = 192;  noff = 0;   break;
    case 1: src = Wa;      dst = t_oa; K = 256;  N = 96;   noff = 192; break;
    case 2: src = nullptr; dst = t_oa; K = 256;  N = 96;   noff = 288; break;
    case 3: src = Wv;      dst = t_v;  K = 256;  N = 256;  noff = 0;   break;
    case 4: src = Wp;      dst = t_p;  K = 256;  N = 256;  noff = 0;   break;
    case 5: src = Wf1;     dst = t_f1; K = 256;  N = 1024; noff = 0;   break;
    default: src = Wf2;    dst = t_f2; K = 1024; N = 256;  noff = 0;   break;
  }
  const int tilesK = K >> 5;
  const int nt = tilesK * (N >> 5);
  if ((int)blockIdx.x >= nt) return;
  const int tk = blockIdx.x % tilesK, tn = blockIdx.x / tilesK;
  const int k0 = tk * 32, n0 = tn * 32;
  const int t = threadIdx.x;
  const int r = t >> 3, c4 = (t & 7) * 4;
  float4 v = make_float4(0.f, 0.f, 0.f, 0.f);
  if (src) v = *(const float4*)(src + (size_t)(k0 + r) * N + n0 + c4);
  tile[r][c4] = v.x; tile[r][c4 + 1] = v.y; tile[r][c4 + 2] = v.z; tile[r][c4 + 3] = v.w;
  __syncthreads();
  const int nn = t >> 3, kc = (t & 7) * 4;
  s16x4 o;
  o.x = f2b(tile[kc][nn]); o.y = f2b(tile[kc + 1][nn]);
  o.z = f2b(tile[kc + 2][nn]); o.w = f2b(tile[kc + 3][nn]);
  *(s16x4*)(dst + (size_t)(noff + n0 + nn) * K + k0 + kc) = o;
}

// ---------------------------------------------------------------------------
// value fp32 [12600x256] -> bf16 [12672x256] (zero-padded rows)
// ---------------------------------------------------------------------------
__global__ __launch_bounds__(256) void vconvert(const float* __restrict__ x,
                                                short* __restrict__ y)
{
  const int i = (blockIdx.x * 256 + threadIdx.x) * 4;
  if (i >= 12672 * 256) return;
  s16x4 o = (s16x4){0, 0, 0, 0};
  if (i < 12600 * 256) {
    float4 v = *(const float4*)(x + i);
    o.x = f2b(v.x); o.y = f2b(v.y); o.z = f2b(v.z); o.w = f2b(v.w);
  }
  *(s16x4*)(y + i) = o;
}

// ---------------------------------------------------------------------------
// LayerNorm: one wave per row of 256.
// ---------------------------------------------------------------------------
__global__ __launch_bounds__(256) void ln_kernel(
    const float* __restrict__ x, const float* __restrict__ pos,
    const float* __restrict__ g, const float* __restrict__ bta,
    float* __restrict__ yf, short* __restrict__ ybf)
{
  const int row  = blockIdx.x * 4 + (threadIdx.x >> 6);
  const int lane = threadIdx.x & 63;
  const float4 v = ((const float4*)(x + (size_t)row * 256))[lane];
  float s = v.x + v.y + v.z + v.w;
#pragma unroll
  for (int o = 32; o; o >>= 1) s += __shfl_xor(s, o);
  const float mean = s * (1.f / 256.f);
  const float dx = v.x - mean, dy = v.y - mean, dz = v.z - mean, dw = v.w - mean;
  float s2 = dx * dx + dy * dy + dz * dz + dw * dw;
#pragma unroll
  for (int o = 32; o; o >>= 1) s2 += __shfl_xor(s2, o);
  const float inv = rsqrtf(s2 * (1.f / 256.f) + 1e-5f);
  const float4 gv = ((const float4*)g)[lane];
  const float4 bv = ((const float4*)bta)[lane];
  float4 o1 = make_float4(dx * inv * gv.x + bv.x, dy * inv * gv.y + bv.y,
                          dz * inv * gv.z + bv.z, dw * inv * gv.w + bv.w);
  if (yf) ((float4*)(yf + (size_t)row * 256))[lane] = o1;
  if (ybf) {
    if (pos) {
      const float4 pv = ((const float4*)(pos + (size_t)row * 256))[lane];
      o1.x += pv.x; o1.y += pv.y; o1.z += pv.z; o1.w += pv.w;
    }
    s16x4 ob; ob.x = f2b(o1.x); ob.y = f2b(o1.y); ob.z = f2b(o1.z); ob.w = f2b(o1.w);
    ((s16x4*)(ybf + (size_t)row * 256))[lane] = ob;
  }
}

// ---------------------------------------------------------------------------
// bf16 MFMA GEMM, m97 structure: 128x128 tile, BK=32, global_load_lds.
// EPI: 1=gelu->bf16 | 2=f32+bias+add1+add2 | 3=f32+bias+add1
//      4=oa (bias split 192/96, f32) | 5=bf16+bias
// ---------------------------------------------------------------------------
template <int EPI>
__global__ __launch_bounds__(256) void gemm_bf16(
    const short* __restrict__ A, const short* __restrict__ Bt,
    const float* __restrict__ bias, const float* __restrict__ bias2,
    const float* __restrict__ add1, const float* __restrict__ add2,
    void* __restrict__ Cout, int M, int Nreal, int ldc, int K)
{
  __shared__ short lA[128 * 32];
  __shared__ short lB[128 * 32];
  const int t = threadIdx.x;
  const int wave = t >> 6, lane = t & 63;
  const int quad = lane >> 4, l16 = lane & 15;
  const int wm = (wave & 1) * 64, wn = (wave >> 1) * 64;
  const int m0 = blockIdx.y * 128, n0 = blockIdx.x * 128;

  f32x4 acc[4][4];
#pragma unroll
  for (int i = 0; i < 4; i++)
#pragma unroll
    for (int j = 0; j < 4; j++) acc[i][j] = (f32x4){0.f, 0.f, 0.f, 0.f};

  const int srow = lane >> 2, skc = (lane & 3) * 8;
  const short* gA = A + (size_t)(m0 + wave * 32 + srow) * K + skc;
  const short* gB = Bt + (size_t)(n0 + wave * 32 + srow) * K + skc;
  short* lAw = lA + wave * 1024;
  short* lBw = lB + wave * 1024;

  for (int k0 = 0; k0 < K; k0 += 32) {
    __syncthreads();
    glds16(gA + k0, lAw);
    glds16(gA + (size_t)16 * K + k0, lAw + 512);
    glds16(gB + k0, lBw);
    glds16(gB + (size_t)16 * K + k0, lBw + 512);
    __syncthreads();

    short8 af[4], bf[4];
#pragma unroll
    for (int i = 0; i < 4; i++) {
      af[i] = *(const short8*)&lA[(wm + i * 16 + l16) * 32 + quad * 8];
      bf[i] = *(const short8*)&lB[(wn + i * 16 + l16) * 32 + quad * 8];
    }
#pragma unroll
    for (int i = 0; i < 4; i++)
#pragma unroll
      for (int j = 0; j < 4; j++) acc[i][j] = mfma16(af[i], bf[j], acc[i][j]);
  }

#pragma unroll
  for (int j = 0; j < 4; j++) {
    const int gn = n0 + wn + j * 16 + l16;
    if (gn >= Nreal) continue;
    float bb;
    if (EPI == 4) bb = (gn < 192) ? bias[gn] : bias2[gn - 192];
    else bb = bias[gn];
#pragma unroll
    for (int i = 0; i < 4; i++) {
#pragma unroll
      for (int r = 0; r < 4; r++) {
        const int gm = m0 + wm + i * 16 + quad * 4 + r;
        if (gm >= M) continue;
        float val = acc[i][j][r] + bb;
        if (EPI == 1) {
          val = 0.5f * val * (1.f + erff(val * 0.70710678118654752f));
          ((short*)Cout)[(size_t)gm * ldc + gn] = f2b(val);
        } else if (EPI == 5) {
          ((short*)Cout)[(size_t)gm * ldc + gn] = f2b(val);
        } else {
          if (EPI == 2) val += add1[(size_t)gm * ldc + gn] + add2[(size_t)gm * ldc + gn];
          if (EPI == 3) val += add1[(size_t)gm * ldc + gn];
          ((float*)Cout)[(size_t)gm * ldc + gn] = val;
        }
      }
    }
  }
}

// ---------------------------------------------------------------------------
// prep_points: one thread per (row, head). Fused softmax + bilinear setup.
// Emits per point: int4 corner element-offsets (clamped, absolute into vproj,
// h*32 folded in) and bf16x4 combined weights (attention x bilinear x valid).
// ---------------------------------------------------------------------------
__global__ __launch_bounds__(256) void prep_points(
    const float* __restrict__ oa, const float* __restrict__ refp,
    int4* __restrict__ tIdx, s16x4* __restrict__ tW)
{
  const int t = blockIdx.x * 256 + threadIdx.x;   // 131072 = 16384*8
  const int row = t >> 3, h = t & 7;
  const float* oarow = oa + (size_t)row * 288;

  float off[24];
  const float4* op = (const float4*)(oarow + h * 24);
#pragma unroll
  for (int i = 0; i < 6; i++) {
    const float4 v = op[i];
    off[i * 4] = v.x; off[i * 4 + 1] = v.y; off[i * 4 + 2] = v.z; off[i * 4 + 3] = v.w;
  }
  float lg[12];
  const float4* ap = (const float4*)(oarow + 192 + h * 12);
#pragma unroll
  for (int i = 0; i < 3; i++) {
    const float4 v = ap[i];
    lg[i * 4] = v.x; lg[i * 4 + 1] = v.y; lg[i * 4 + 2] = v.z; lg[i * 4 + 3] = v.w;
  }
  const float* rp = refp + (size_t)row * 6;
  const float r0x = rp[0], r0y = rp[1], r1x = rp[2], r1y = rp[3], r2x = rp[4], r2y = rp[5];

  float mx = lg[0];
#pragma unroll
  for (int i = 1; i < 12; i++) mx = fmaxf(mx, lg[i]);
  float sum = 0.f;
#pragma unroll
  for (int i = 0; i < 12; i++) { lg[i] = __expf(lg[i] - mx); sum += lg[i]; }
  const float inv = 1.f / sum;

  const int b = row >> 13;
  const int Hs[3] = {60, 30, 15}, Ws[3] = {80, 40, 20}, St[3] = {0, 4800, 6000};
  const float Rx[3] = {r0x, r1x, r2x}, Ry[3] = {r0y, r1y, r2y};

  int4* ti = tIdx + (size_t)t * 12;
  s16x4* tw = tW + (size_t)t * 12;
#pragma unroll
  for (int p = 0; p < 12; p++) {
    const int l = p >> 2;
    const int W = Ws[l], H = Hs[l];
    const float gx = Rx[l] * W + off[p * 2]     - 0.5f;
    const float gy = Ry[l] * H + off[p * 2 + 1] - 0.5f;
    const float x0f = floorf(gx), y0f = floorf(gy);
    const float wx = gx - x0f, wy = gy - y0f;
    const int x0 = (int)x0f, y0 = (int)y0f;
    const float aw = lg[p] * inv;
    float cw[4] = {(1.f - wx) * (1.f - wy), wx * (1.f - wy),
                   (1.f - wx) * wy, wx * wy};
    const int base = b * 6300 + St[l];
    int ci[4];
#pragma unroll
    for (int k = 0; k < 4; k++) {
      const int xx = x0 + (k & 1), yy = y0 + (k >> 1);
      const bool valid = (xx >= 0) & (xx < W) & (yy >= 0) & (yy < H);
      const int xc = min(max(xx, 0), W - 1);
      const int yc = min(max(yy, 0), H - 1);
      ci[k] = ((base + yc * W + xc) << 8) + h * 32;
      cw[k] = valid ? cw[k] * aw : 0.f;
    }
    ti[p] = make_int4(ci[0], ci[1], ci[2], ci[3]);
    s16x4 wv; wv.x = f2b(cw[0]); wv.y = f2b(cw[1]); wv.z = f2b(cw[2]); wv.w = f2b(cw[3]);
    tw[p] = wv;
  }
}

// ---------------------------------------------------------------------------
// deform_gather: thread = (row, h, c4); c4 covers 8 channels via 16 B loads.
// Pure gather+FMA: no address math, no branches, low VGPR.
// ---------------------------------------------------------------------------
__global__ __launch_bounds__(256) void deform_gather(
    const short* __restrict__ vproj, const int4* __restrict__ tIdx,
    const s16x4* __restrict__ tW, short* __restrict__ out)
{
  const int t = blockIdx.x * 256 + threadIdx.x;  // 524288 = 16384*8*4
  const int unit = t >> 2, c4 = (t & 3) * 8;
  const int4* ip = tIdx + (size_t)unit * 12;
  const s16x4* wp = tW + (size_t)unit * 12;
  float acc[8];
#pragma unroll
  for (int i = 0; i < 8; i++) acc[i] = 0.f;

#pragma unroll 2
  for (int p = 0; p < 12; p++) {
    const int4 idx = ip[p];
    const s16x4 wb = wp[p];
    const float w0 = b2f(wb.x), w1 = b2f(wb.y), w2 = b2f(wb.z), w3 = b2f(wb.w);
    const short8 v0 = *(const short8*)(vproj + idx.x + c4);
    const short8 v1 = *(const short8*)(vproj + idx.y + c4);
    const short8 v2 = *(const short8*)(vproj + idx.z + c4);
    const short8 v3 = *(const short8*)(vproj + idx.w + c4);
    float f0[8], f1[8], f2[8], f3[8];
    b8f(v0, f0); b8f(v1, f1); b8f(v2, f2); b8f(v3, f3);
#pragma unroll
    for (int j = 0; j < 8; j++)
      acc[j] += w0 * f0[j] + w1 * f1[j] + w2 * f2[j] + w3 * f3[j];
  }
  short8 o;
#pragma unroll
  for (int j = 0; j < 8; j++) o[j] = f2b(acc[j]);
  *(short8*)(out + (size_t)t * 8) = o;
}

// ---------------------------------------------------------------------------
// Launch
// ---------------------------------------------------------------------------
extern "C" void kernel_launch(void* const* d_in, const int* in_sizes, int n_in,
                              void* d_out, int out_size, void* d_ws, size_t ws_size,
                              hipStream_t stream)
{
  const float* query     = (const float*)d_in[0];
  const float* value     = (const float*)d_in[1];
  const float* query_pos = (const float*)d_in[2];
  const float* ref_pts   = (const float*)d_in[3];
  const float* g1  = (const float*)d_in[6];
  const float* b1  = (const float*)d_in[7];
  const float* Wo  = (const float*)d_in[8];
  const float* bo  = (const float*)d_in[9];
  const float* Wa  = (const float*)d_in[10];
  const float* ba  = (const float*)d_in[11];
  const float* Wv  = (const float*)d_in[12];
  const float* bv  = (const float*)d_in[13];
  const float* Wp  = (const float*)d_in[14];
  const float* bp  = (const float*)d_in[15];
  const float* g2  = (const float*)d_in[16];
  const float* b2  = (const float*)d_in[17];
  const float* Wf1 = (const float*)d_in[18];
  const float* bf1 = (const float*)d_in[19];
  const float* Wf2 = (const float*)d_in[20];
  const float* bf2 = (const float*)d_in[21];

  char* ws = (char*)d_ws;
  // Byte offsets; lifetime-overlapped, total 98,136,064 B.
  short* wt_oa   = (short*)(ws + 0);
  short* wt_v    = (short*)(ws + 196608);
  short* wt_p    = (short*)(ws + 327680);
  short* wt_f1   = (short*)(ws + 458752);
  short* wt_f2   = (short*)(ws + 983040);
  float* qn      = (float*)(ws + 1507328);    // 16384x256 f32
  short* qa      = (short*)(ws + 18284544);   // 16384x256 bf16 (later q2)
  float* oabuf   = (float*)(ws + 26673152);   // 16384x288 f32 (dead after prep)
  short* vproj   = (short*)(ws + 45547520);   // 12600x256 bf16
  short* sampled = (short*)(ws + 51998720);   // 16384x256 bf16
  float* qbuf    = (float*)(ws + 60387328);   // 16384x256 f32 (written AFTER tables die)
  short* valbf   = (short*)(ws + 77164544);   // 12672x256 bf16 (dead after vproj GEMM)
  int4*  tIdx    = (int4*)(ws + 60387328);    // 131072x12x16 B, overlaps qbuf+valbf
  s16x4* tW      = (s16x4*)(ws + 85553152);   // 131072x12x8 B -> end 98,136,064
  short* q2      = qa;
  short* hidden  = (short*)(ws + 26673152);   // 16384x1024 bf16 over oabuf+vproj+sampled
  float* outp = (float*)d_out;

  // NOTE ordering constraints: tIdx/tW overlap valbf -> prep_points must run
  // AFTER the vproj GEMM consumed valbf; qbuf overlaps tables -> Wp GEMM runs
  // after gather consumed them. Stream-serial, so order below enforces it.

  wconvert<<<dim3(256, 7), 256, 0, stream>>>(Wo, Wa, Wv, Wp, Wf1, Wf2,
                                             wt_oa, wt_v, wt_p, wt_f1, wt_f2);
  vconvert<<<3169, 256, 0, stream>>>(value, valbf);
  // qn = LN(query) f32; qa = (qn + pos) bf16
  ln_kernel<<<4096, 256, 0, stream>>>(query, query_pos, g1, b1, qn, qa);
  // oa = qa @ [Wo|Wa] + [bo|ba]   [16384 x 288] f32 (raw logits)
  gemm_bf16<4><<<dim3(3, 128), 256, 0, stream>>>(qa, wt_oa, bo, ba, nullptr,
                                                 nullptr, oabuf, 16384, 288, 288, 256);
  // vproj = value @ Wv + bv -> bf16   [12600 x 256]
  gemm_bf16<5><<<dim3(2, 99), 256, 0, stream>>>(valbf, wt_v, bv, nullptr, nullptr,
                                                nullptr, vproj, 12600, 256, 256, 256);
  // tables (softmax fused)
  prep_points<<<512, 256, 0, stream>>>(oabuf, ref_pts, tIdx, tW);
  // gather -> sampled bf16 [16384 x 256]
  deform_gather<<<2048, 256, 0, stream>>>(vproj, tIdx, tW, sampled);
  // qbuf = sampled @ Wp + bp + qn + query   f32
  gemm_bf16<2><<<dim3(2, 128), 256, 0, stream>>>(sampled, wt_p, bp, nullptr, qn,
                                                 (const float*)query, qbuf,
                                                 16384, 256, 256, 256);
  // q2 = LN(qbuf) bf16
  ln_kernel<<<4096, 256, 0, stream>>>(qbuf, nullptr, g2, b2, nullptr, q2);
  // hidden = gelu(q2 @ Wf1 + bf1) bf16   [16384 x 1024]
  gemm_bf16<1><<<dim3(8, 128), 256, 0, stream>>>(q2, wt_f1, bf1, nullptr, nullptr,
                                                 nullptr, hidden, 16384, 1024, 1024, 256);
  // out = qbuf + hidden @ Wf2 + bf2   f32
  gemm_bf16<3><<<dim3(2, 128), 256, 0, stream>>>(hidden, wt_f2, bf2, nullptr, qbuf,
                                                 nullptr, outp, 16384, 256, 256, 1024);
}

// Round 5
// 308.923 us; speedup vs baseline: 1.6504x; 1.1663x over previous
//
#include <hip/hip_runtime.h>
#include <math.h>

// ---------------------------------------------------------------------------
// Deformable transformer layer, MI355X round-5 (round-4 + swizzle sign fix):
//  - GEMM: operand-swapped MFMA (row-major acc -> coalesced 8/16B C stores),
//    double-buffered LDS with prefetch-at-top, bank-conflict-reduced swizzle.
//  - two-phase deform sampling (prep tables + lean gather).
// B=2, Nq=8192, C=256, HEADS=8, dh=32, LEVELS=3, POINTS=4, MLP=4
// ---------------------------------------------------------------------------

typedef short short8 __attribute__((ext_vector_type(8)));
typedef short s16x4 __attribute__((ext_vector_type(4)));
typedef __bf16 bf16x8 __attribute__((ext_vector_type(8)));
typedef float f32x4 __attribute__((ext_vector_type(4)));

__device__ __forceinline__ short f2b(float f) {
  unsigned u = __builtin_bit_cast(unsigned, f);
  u += 0x7fffu + ((u >> 16) & 1u);   // RNE to bf16
  return (short)(u >> 16);
}
__device__ __forceinline__ float b2f(short s) {
  unsigned u = ((unsigned)(unsigned short)s) << 16;
  return __builtin_bit_cast(float, u);
}
__device__ __forceinline__ void b8f(short8 s, float* f) {
  const uint4 u = __builtin_bit_cast(uint4, s);
  f[0] = __builtin_bit_cast(float, u.x << 16);
  f[1] = __builtin_bit_cast(float, u.x & 0xffff0000u);
  f[2] = __builtin_bit_cast(float, u.y << 16);
  f[3] = __builtin_bit_cast(float, u.y & 0xffff0000u);
  f[4] = __builtin_bit_cast(float, u.z << 16);
  f[5] = __builtin_bit_cast(float, u.z & 0xffff0000u);
  f[6] = __builtin_bit_cast(float, u.w << 16);
  f[7] = __builtin_bit_cast(float, u.w & 0xffff0000u);
}

__device__ __forceinline__ f32x4 mfma16(short8 a, short8 b, f32x4 c) {
  return __builtin_amdgcn_mfma_f32_16x16x32_bf16(
      __builtin_bit_cast(bf16x8, a), __builtin_bit_cast(bf16x8, b), c, 0, 0, 0);
}

typedef __attribute__((address_space(3))) unsigned int lds_u32;
typedef const __attribute__((address_space(1))) unsigned int glb_u32;
__device__ __forceinline__ void glds16(const void* g, void* l) {
  __builtin_amdgcn_global_load_lds((glb_u32*)g, (lds_u32*)l, 16, 0, 0);
}

// ---------------------------------------------------------------------------
// Weight convert + transpose: Wt[n][k] bf16 from W[k][n] fp32.
// ---------------------------------------------------------------------------
__global__ __launch_bounds__(256) void wconvert(
    const float* __restrict__ Wo, const float* __restrict__ Wa,
    const float* __restrict__ Wv, const float* __restrict__ Wp,
    const float* __restrict__ Wf1, const float* __restrict__ Wf2,
    short* __restrict__ t_oa, short* __restrict__ t_v, short* __restrict__ t_p,
    short* __restrict__ t_f1, short* __restrict__ t_f2)
{
  __shared__ float tile[32][33];
  int K, N, noff; const float* src; short* dst;
  switch (blockIdx.y) {
    case 0: src = Wo;      dst = t_oa; K = 256;  N = 192;  noff = 0;   break;
    case 1: src = Wa;      dst = t_oa; K = 256;  N = 96;   noff = 192; break;
    case 2: src = nullptr; dst = t_oa; K = 256;  N = 96;   noff = 288; break;
    case 3: src = Wv;      dst = t_v;  K = 256;  N = 256;  noff = 0;   break;
    case 4: src = Wp;      dst = t_p;  K = 256;  N = 256;  noff = 0;   break;
    case 5: src = Wf1;     dst = t_f1; K = 256;  N = 1024; noff = 0;   break;
    default: src = Wf2;    dst = t_f2; K = 1024; N = 256;  noff = 0;   break;
  }
  const int tilesK = K >> 5;
  const int nt = tilesK * (N >> 5);
  if ((int)blockIdx.x >= nt) return;
  const int tk = blockIdx.x % tilesK, tn = blockIdx.x / tilesK;
  const int k0 = tk * 32, n0 = tn * 32;
  const int t = threadIdx.x;
  const int r = t >> 3, c4 = (t & 7) * 4;
  float4 v = make_float4(0.f, 0.f, 0.f, 0.f);
  if (src) v = *(const float4*)(src + (size_t)(k0 + r) * N + n0 + c4);
  tile[r][c4] = v.x; tile[r][c4 + 1] = v.y; tile[r][c4 + 2] = v.z; tile[r][c4 + 3] = v.w;
  __syncthreads();
  const int nn = t >> 3, kc = (t & 7) * 4;
  s16x4 o;
  o.x = f2b(tile[kc][nn]); o.y = f2b(tile[kc + 1][nn]);
  o.z = f2b(tile[kc + 2][nn]); o.w = f2b(tile[kc + 3][nn]);
  *(s16x4*)(dst + (size_t)(noff + n0 + nn) * K + k0 + kc) = o;
}

// ---------------------------------------------------------------------------
// value fp32 [12600x256] -> bf16 [12672x256] (zero-padded rows)
// ---------------------------------------------------------------------------
__global__ __launch_bounds__(256) void vconvert(const float* __restrict__ x,
                                                short* __restrict__ y)
{
  const int i = (blockIdx.x * 256 + threadIdx.x) * 4;
  if (i >= 12672 * 256) return;
  s16x4 o = (s16x4){0, 0, 0, 0};
  if (i < 12600 * 256) {
    float4 v = *(const float4*)(x + i);
    o.x = f2b(v.x); o.y = f2b(v.y); o.z = f2b(v.z); o.w = f2b(v.w);
  }
  *(s16x4*)(y + i) = o;
}

// ---------------------------------------------------------------------------
// LayerNorm: one wave per row of 256.
// ---------------------------------------------------------------------------
__global__ __launch_bounds__(256) void ln_kernel(
    const float* __restrict__ x, const float* __restrict__ pos,
    const float* __restrict__ g, const float* __restrict__ bta,
    float* __restrict__ yf, short* __restrict__ ybf)
{
  const int row  = blockIdx.x * 4 + (threadIdx.x >> 6);
  const int lane = threadIdx.x & 63;
  const float4 v = ((const float4*)(x + (size_t)row * 256))[lane];
  float s = v.x + v.y + v.z + v.w;
#pragma unroll
  for (int o = 32; o; o >>= 1) s += __shfl_xor(s, o);
  const float mean = s * (1.f / 256.f);
  const float dx = v.x - mean, dy = v.y - mean, dz = v.z - mean, dw = v.w - mean;
  float s2 = dx * dx + dy * dy + dz * dz + dw * dw;
#pragma unroll
  for (int o = 32; o; o >>= 1) s2 += __shfl_xor(s2, o);
  const float inv = rsqrtf(s2 * (1.f / 256.f) + 1e-5f);
  const float4 gv = ((const float4*)g)[lane];
  const float4 bv = ((const float4*)bta)[lane];
  float4 o1 = make_float4(dx * inv * gv.x + bv.x, dy * inv * gv.y + bv.y,
                          dz * inv * gv.z + bv.z, dw * inv * gv.w + bv.w);
  if (yf) ((float4*)(yf + (size_t)row * 256))[lane] = o1;
  if (ybf) {
    if (pos) {
      const float4 pv = ((const float4*)(pos + (size_t)row * 256))[lane];
      o1.x += pv.x; o1.y += pv.y; o1.z += pv.z; o1.w += pv.w;
    }
    s16x4 ob; ob.x = f2b(o1.x); ob.y = f2b(o1.y); ob.z = f2b(o1.z); ob.w = f2b(o1.w);
    ((s16x4*)(ybf + (size_t)row * 256))[lane] = ob;
  }
}

// ---------------------------------------------------------------------------
// bf16 MFMA GEMM: 128x128 tile, BK=32, double-buffered LDS prefetch-at-top,
// swizzled staging (store chunk (p+(srow>>1))&3 -> read p=(quad-(l16>>1))&3),
// operand-swapped MFMA (lane holds 4 consecutive C columns of one row).
// EPI: 1=gelu->bf16 | 2=f32+bias+add1+add2 | 3=f32+bias+add1
//      4=oa (bias split 192/96, f32) | 5=bf16+bias
// ---------------------------------------------------------------------------
template <int EPI>
__global__ __launch_bounds__(256) void gemm_bf16(
    const short* __restrict__ A, const short* __restrict__ Bt,
    const float* __restrict__ bias, const float* __restrict__ bias2,
    const float* __restrict__ add1, const float* __restrict__ add2,
    void* __restrict__ Cout, int M, int Nreal, int ldc, int K)
{
  __shared__ short lA[2][128 * 32];
  __shared__ short lB[2][128 * 32];
  const int t = threadIdx.x;
  const int wave = t >> 6, lane = t & 63;
  const int quad = lane >> 4, l16 = lane & 15;
  const int wm = (wave & 1) * 64, wn = (wave >> 1) * 64;
  const int m0 = blockIdx.y * 128, n0 = blockIdx.x * 128;

  f32x4 acc[4][4];
#pragma unroll
  for (int i = 0; i < 4; i++)
#pragma unroll
    for (int j = 0; j < 4; j++) acc[i][j] = (f32x4){0.f, 0.f, 0.f, 0.f};

  // Staging: lane L = srow*4+p stages k-chunk ((L&3)+(L>>3))&3 = (p+(srow>>1))&3
  // of row srow at LDS position p (glds dest = base + L*16B).
  const int srow = lane >> 2;
  const int skc = (((lane & 3) + (lane >> 3)) & 3) * 8;
  const short* gA = A + (size_t)(m0 + wave * 32 + srow) * K + skc;
  const short* gB = Bt + (size_t)(n0 + wave * 32 + srow) * K + skc;
  const int lw = wave * 1024;  // shorts; 16-row slice = 512 shorts per glds

  // prologue: fill buffer 0
  glds16(gA, &lA[0][lw]);
  glds16(gA + (size_t)16 * K, &lA[0][lw + 512]);
  glds16(gB, &lB[0][lw]);
  glds16(gB + (size_t)16 * K, &lB[0][lw + 512]);
  __syncthreads();

  // read position for chunk `quad` in row with local index l16 (sign fix!)
  const int rchunk = ((quad - (l16 >> 1)) & 3) * 8;
  const int nk = K >> 5;
  for (int k = 0; k < nk; ++k) {
    const int cur = k & 1;
    if (k + 1 < nk) {
      const int nxt = cur ^ 1;
      const short* pA = gA + (size_t)(k + 1) * 32;
      const short* pB = gB + (size_t)(k + 1) * 32;
      glds16(pA, &lA[nxt][lw]);
      glds16(pA + (size_t)16 * K, &lA[nxt][lw + 512]);
      glds16(pB, &lB[nxt][lw]);
      glds16(pB + (size_t)16 * K, &lB[nxt][lw + 512]);
    }
    short8 af[4], bf[4];
#pragma unroll
    for (int i = 0; i < 4; i++) {
      af[i] = *(const short8*)&lA[cur][(wm + i * 16 + l16) * 32 + rchunk];
      bf[i] = *(const short8*)&lB[cur][(wn + i * 16 + l16) * 32 + rchunk];
    }
    // SWAPPED operands: l16 -> C row (af side), quad*4+r -> C col (bf side)
#pragma unroll
    for (int i = 0; i < 4; i++)
#pragma unroll
      for (int j = 0; j < 4; j++) acc[i][j] = mfma16(bf[j], af[i], acc[i][j]);
    __syncthreads();
  }

  // Epilogue: lane owns rows (m0+wm+i*16+l16), col chunks (n0+wn+j*16+quad*4).
  const int row_ = m0 + wm + l16;
  const int col_ = n0 + wn + quad * 4;
#pragma unroll
  for (int j = 0; j < 4; j++) {
    const int cc = col_ + j * 16;
    if (cc >= Nreal) continue;
    float4 bb;
    if (EPI == 4) bb = (cc < 192) ? *(const float4*)(bias + cc)
                                  : *(const float4*)(bias2 + cc - 192);
    else bb = *(const float4*)(bias + cc);
#pragma unroll
    for (int i = 0; i < 4; i++) {
      const int gm = row_ + i * 16;
      if (gm >= M) continue;
      float v0 = acc[i][j][0] + bb.x, v1 = acc[i][j][1] + bb.y;
      float v2 = acc[i][j][2] + bb.z, v3 = acc[i][j][3] + bb.w;
      if (EPI == 1) {
        v0 = 0.5f * v0 * (1.f + erff(v0 * 0.70710678118654752f));
        v1 = 0.5f * v1 * (1.f + erff(v1 * 0.70710678118654752f));
        v2 = 0.5f * v2 * (1.f + erff(v2 * 0.70710678118654752f));
        v3 = 0.5f * v3 * (1.f + erff(v3 * 0.70710678118654752f));
        s16x4 o; o.x = f2b(v0); o.y = f2b(v1); o.z = f2b(v2); o.w = f2b(v3);
        *(s16x4*)((short*)Cout + (size_t)gm * ldc + cc) = o;
      } else if (EPI == 5) {
        s16x4 o; o.x = f2b(v0); o.y = f2b(v1); o.z = f2b(v2); o.w = f2b(v3);
        *(s16x4*)((short*)Cout + (size_t)gm * ldc + cc) = o;
      } else {
        if (EPI == 2 || EPI == 3) {
          const float4 a1 = *(const float4*)(add1 + (size_t)gm * ldc + cc);
          v0 += a1.x; v1 += a1.y; v2 += a1.z; v3 += a1.w;
          if (EPI == 2) {
            const float4 a2 = *(const float4*)(add2 + (size_t)gm * ldc + cc);
            v0 += a2.x; v1 += a2.y; v2 += a2.z; v3 += a2.w;
          }
        }
        *(float4*)((float*)Cout + (size_t)gm * ldc + cc) =
            make_float4(v0, v1, v2, v3);
      }
    }
  }
}

// ---------------------------------------------------------------------------
// prep_points: one thread per (row, head). Fused softmax + bilinear setup.
// ---------------------------------------------------------------------------
__global__ __launch_bounds__(256) void prep_points(
    const float* __restrict__ oa, const float* __restrict__ refp,
    int4* __restrict__ tIdx, s16x4* __restrict__ tW)
{
  const int t = blockIdx.x * 256 + threadIdx.x;   // 131072 = 16384*8
  const int row = t >> 3, h = t & 7;
  const float* oarow = oa + (size_t)row * 288;

  float off[24];
  const float4* op = (const float4*)(oarow + h * 24);
#pragma unroll
  for (int i = 0; i < 6; i++) {
    const float4 v = op[i];
    off[i * 4] = v.x; off[i * 4 + 1] = v.y; off[i * 4 + 2] = v.z; off[i * 4 + 3] = v.w;
  }
  float lg[12];
  const float4* ap = (const float4*)(oarow + 192 + h * 12);
#pragma unroll
  for (int i = 0; i < 3; i++) {
    const float4 v = ap[i];
    lg[i * 4] = v.x; lg[i * 4 + 1] = v.y; lg[i * 4 + 2] = v.z; lg[i * 4 + 3] = v.w;
  }
  const float* rp = refp + (size_t)row * 6;
  const float Rx[3] = {rp[0], rp[2], rp[4]}, Ry[3] = {rp[1], rp[3], rp[5]};

  float mx = lg[0];
#pragma unroll
  for (int i = 1; i < 12; i++) mx = fmaxf(mx, lg[i]);
  float sum = 0.f;
#pragma unroll
  for (int i = 0; i < 12; i++) { lg[i] = __expf(lg[i] - mx); sum += lg[i]; }
  const float inv = 1.f / sum;

  const int b = row >> 13;
  const int Hs[3] = {60, 30, 15}, Ws[3] = {80, 40, 20}, St[3] = {0, 4800, 6000};

  int4* ti = tIdx + (size_t)t * 12;
  s16x4* tw = tW + (size_t)t * 12;
#pragma unroll
  for (int p = 0; p < 12; p++) {
    const int l = p >> 2;
    const int W = Ws[l], H = Hs[l];
    const float gx = Rx[l] * W + off[p * 2]     - 0.5f;
    const float gy = Ry[l] * H + off[p * 2 + 1] - 0.5f;
    const float x0f = floorf(gx), y0f = floorf(gy);
    const float wx = gx - x0f, wy = gy - y0f;
    const int x0 = (int)x0f, y0 = (int)y0f;
    const float aw = lg[p] * inv;
    float cw[4] = {(1.f - wx) * (1.f - wy), wx * (1.f - wy),
                   (1.f - wx) * wy, wx * wy};
    const int base = b * 6300 + St[l];
    int ci[4];
#pragma unroll
    for (int k = 0; k < 4; k++) {
      const int xx = x0 + (k & 1), yy = y0 + (k >> 1);
      const bool valid = (xx >= 0) & (xx < W) & (yy >= 0) & (yy < H);
      const int xc = min(max(xx, 0), W - 1);
      const int yc = min(max(yy, 0), H - 1);
      ci[k] = ((base + yc * W + xc) << 8) + h * 32;
      cw[k] = valid ? cw[k] * aw : 0.f;
    }
    ti[p] = make_int4(ci[0], ci[1], ci[2], ci[3]);
    s16x4 wv; wv.x = f2b(cw[0]); wv.y = f2b(cw[1]); wv.z = f2b(cw[2]); wv.w = f2b(cw[3]);
    tw[p] = wv;
  }
}

// ---------------------------------------------------------------------------
// deform_gather: thread = (row, h, c4); c4 covers 8 channels via 16 B loads.
// ---------------------------------------------------------------------------
__global__ __launch_bounds__(256) void deform_gather(
    const short* __restrict__ vproj, const int4* __restrict__ tIdx,
    const s16x4* __restrict__ tW, short* __restrict__ out)
{
  const int t = blockIdx.x * 256 + threadIdx.x;  // 524288 = 16384*8*4
  const int unit = t >> 2, c4 = (t & 3) * 8;
  const int4* ip = tIdx + (size_t)unit * 12;
  const s16x4* wp = tW + (size_t)unit * 12;
  float acc[8];
#pragma unroll
  for (int i = 0; i < 8; i++) acc[i] = 0.f;

#pragma unroll 2
  for (int p = 0; p < 12; p++) {
    const int4 idx = ip[p];
    const s16x4 wb = wp[p];
    const float w0 = b2f(wb.x), w1 = b2f(wb.y), w2 = b2f(wb.z), w3 = b2f(wb.w);
    const short8 v0 = *(const short8*)(vproj + idx.x + c4);
    const short8 v1 = *(const short8*)(vproj + idx.y + c4);
    const short8 v2 = *(const short8*)(vproj + idx.z + c4);
    const short8 v3 = *(const short8*)(vproj + idx.w + c4);
    float f0[8], f1[8], f2[8], f3[8];
    b8f(v0, f0); b8f(v1, f1); b8f(v2, f2); b8f(v3, f3);
#pragma unroll
    for (int j = 0; j < 8; j++)
      acc[j] += w0 * f0[j] + w1 * f1[j] + w2 * f2[j] + w3 * f3[j];
  }
  short8 o;
#pragma unroll
  for (int j = 0; j < 8; j++) o[j] = f2b(acc[j]);
  *(short8*)(out + (size_t)t * 8) = o;
}

// ---------------------------------------------------------------------------
// Launch
// ---------------------------------------------------------------------------
extern "C" void kernel_launch(void* const* d_in, const int* in_sizes, int n_in,
                              void* d_out, int out_size, void* d_ws, size_t ws_size,
                              hipStream_t stream)
{
  const float* query     = (const float*)d_in[0];
  const float* value     = (const float*)d_in[1];
  const float* query_pos = (const float*)d_in[2];
  const float* ref_pts   = (const float*)d_in[3];
  const float* g1  = (const float*)d_in[6];
  const float* b1  = (const float*)d_in[7];
  const float* Wo  = (const float*)d_in[8];
  const float* bo  = (const float*)d_in[9];
  const float* Wa  = (const float*)d_in[10];
  const float* ba  = (const float*)d_in[11];
  const float* Wv  = (const float*)d_in[12];
  const float* bv  = (const float*)d_in[13];
  const float* Wp  = (const float*)d_in[14];
  const float* bp  = (const float*)d_in[15];
  const float* g2  = (const float*)d_in[16];
  const float* b2  = (const float*)d_in[17];
  const float* Wf1 = (const float*)d_in[18];
  const float* bf1 = (const float*)d_in[19];
  const float* Wf2 = (const float*)d_in[20];
  const float* bf2 = (const float*)d_in[21];

  char* ws = (char*)d_ws;
  short* wt_oa   = (short*)(ws + 0);
  short* wt_v    = (short*)(ws + 196608);
  short* wt_p    = (short*)(ws + 327680);
  short* wt_f1   = (short*)(ws + 458752);
  short* wt_f2   = (short*)(ws + 983040);
  float* qn      = (float*)(ws + 1507328);    // 16384x256 f32
  short* qa      = (short*)(ws + 18284544);   // 16384x256 bf16 (later q2)
  float* oabuf   = (float*)(ws + 26673152);   // 16384x288 f32 (dead after prep)
  short* vproj   = (short*)(ws + 45547520);   // 12600x256 bf16
  short* sampled = (short*)(ws + 51998720);   // 16384x256 bf16
  float* qbuf    = (float*)(ws + 60387328);   // 16384x256 f32 (after tables die)
  short* valbf   = (short*)(ws + 77164544);   // 12672x256 bf16
  int4*  tIdx    = (int4*)(ws + 60387328);    // overlaps qbuf+valbf
  s16x4* tW      = (s16x4*)(ws + 85553152);   // end 98,136,064
  short* q2      = qa;
  short* hidden  = (short*)(ws + 26673152);   // 16384x1024 bf16
  float* outp = (float*)d_out;

  wconvert<<<dim3(256, 7), 256, 0, stream>>>(Wo, Wa, Wv, Wp, Wf1, Wf2,
                                             wt_oa, wt_v, wt_p, wt_f1, wt_f2);
  vconvert<<<3169, 256, 0, stream>>>(value, valbf);
  ln_kernel<<<4096, 256, 0, stream>>>(query, query_pos, g1, b1, qn, qa);
  // oa = qa @ [Wo|Wa] + [bo|ba]   [16384 x 288] f32 (raw logits)
  gemm_bf16<4><<<dim3(3, 128), 256, 0, stream>>>(qa, wt_oa, bo, ba, nullptr,
                                                 nullptr, oabuf, 16384, 288, 288, 256);
  // vproj = value @ Wv + bv -> bf16   [12600 x 256]
  gemm_bf16<5><<<dim3(2, 99), 256, 0, stream>>>(valbf, wt_v, bv, nullptr, nullptr,
                                                nullptr, vproj, 12600, 256, 256, 256);
  prep_points<<<512, 256, 0, stream>>>(oabuf, ref_pts, tIdx, tW);
  deform_gather<<<2048, 256, 0, stream>>>(vproj, tIdx, tW, sampled);
  // qbuf = sampled @ Wp + bp + qn + query   f32
  gemm_bf16<2><<<dim3(2, 128), 256, 0, stream>>>(sampled, wt_p, bp, nullptr, qn,
                                                 (const float*)query, qbuf,
                                                 16384, 256, 256, 256);
  ln_kernel<<<4096, 256, 0, stream>>>(qbuf, nullptr, g2, b2, nullptr, q2);
  // hidden = gelu(q2 @ Wf1 + bf1) bf16   [16384 x 1024]
  gemm_bf16<1><<<dim3(8, 128), 256, 0, stream>>>(q2, wt_f1, bf1, nullptr, nullptr,
                                                 nullptr, hidden, 16384, 1024, 1024, 256);
  // out = qbuf + hidden @ Wf2 + bf2   f32
  gemm_bf16<3><<<dim3(2, 128), 256, 0, stream>>>(hidden, wt_f2, bf2, nullptr, qbuf,
                                                 nullptr, outp, 16384, 256, 256, 1024);
}

// Round 6
// 288.133 us; speedup vs baseline: 1.7695x; 1.0722x over previous
//
#include <hip/hip_runtime.h>
#include <math.h>

// ---------------------------------------------------------------------------
// Deformable transformer layer, MI355X round-6:
//  - GEMM: 128x128 tile, BK=64, single-buffer two-barrier K-loop (proven
//    structure; 32 MFMAs per vmcnt drain), 8-chunk rotation swizzle
//    (conflict-free), operand-swapped MFMA, LDS-staged epilogue giving
//    full-cacheline coalesced C stores (+ coalesced residual loads).
//  - two-phase deform sampling (prep tables + lean gather).
// B=2, Nq=8192, C=256, HEADS=8, dh=32, LEVELS=3, POINTS=4, MLP=4
// ---------------------------------------------------------------------------

typedef short short8 __attribute__((ext_vector_type(8)));
typedef short s16x4 __attribute__((ext_vector_type(4)));
typedef __bf16 bf16x8 __attribute__((ext_vector_type(8)));
typedef float f32x4 __attribute__((ext_vector_type(4)));

__device__ __forceinline__ short f2b(float f) {
  unsigned u = __builtin_bit_cast(unsigned, f);
  u += 0x7fffu + ((u >> 16) & 1u);   // RNE to bf16
  return (short)(u >> 16);
}
__device__ __forceinline__ float b2f(short s) {
  unsigned u = ((unsigned)(unsigned short)s) << 16;
  return __builtin_bit_cast(float, u);
}
__device__ __forceinline__ void b8f(short8 s, float* f) {
  const uint4 u = __builtin_bit_cast(uint4, s);
  f[0] = __builtin_bit_cast(float, u.x << 16);
  f[1] = __builtin_bit_cast(float, u.x & 0xffff0000u);
  f[2] = __builtin_bit_cast(float, u.y << 16);
  f[3] = __builtin_bit_cast(float, u.y & 0xffff0000u);
  f[4] = __builtin_bit_cast(float, u.z << 16);
  f[5] = __builtin_bit_cast(float, u.z & 0xffff0000u);
  f[6] = __builtin_bit_cast(float, u.w << 16);
  f[7] = __builtin_bit_cast(float, u.w & 0xffff0000u);
}

__device__ __forceinline__ f32x4 mfma16(short8 a, short8 b, f32x4 c) {
  return __builtin_amdgcn_mfma_f32_16x16x32_bf16(
      __builtin_bit_cast(bf16x8, a), __builtin_bit_cast(bf16x8, b), c, 0, 0, 0);
}

typedef __attribute__((address_space(3))) unsigned int lds_u32;
typedef const __attribute__((address_space(1))) unsigned int glb_u32;
__device__ __forceinline__ void glds16(const void* g, void* l) {
  __builtin_amdgcn_global_load_lds((glb_u32*)g, (lds_u32*)l, 16, 0, 0);
}

__device__ __forceinline__ float gelu1(float v) {
  return 0.5f * v * (1.f + erff(v * 0.70710678118654752f));
}

// ---------------------------------------------------------------------------
// Weight convert + transpose: Wt[n][k] bf16 from W[k][n] fp32.
// ---------------------------------------------------------------------------
__global__ __launch_bounds__(256) void wconvert(
    const float* __restrict__ Wo, const float* __restrict__ Wa,
    const float* __restrict__ Wv, const float* __restrict__ Wp,
    const float* __restrict__ Wf1, const float* __restrict__ Wf2,
    short* __restrict__ t_oa, short* __restrict__ t_v, short* __restrict__ t_p,
    short* __restrict__ t_f1, short* __restrict__ t_f2)
{
  __shared__ float tile[32][33];
  int K, N, noff; const float* src; short* dst;
  switch (blockIdx.y) {
    case 0: src = Wo;      dst = t_oa; K = 256;  N = 192;  noff = 0;   break;
    case 1: src = Wa;      dst = t_oa; K = 256;  N = 96;   noff = 192; break;
    case 2: src = nullptr; dst = t_oa; K = 256;  N = 96;   noff = 288; break;
    case 3: src = Wv;      dst = t_v;  K = 256;  N = 256;  noff = 0;   break;
    case 4: src = Wp;      dst = t_p;  K = 256;  N = 256;  noff = 0;   break;
    case 5: src = Wf1;     dst = t_f1; K = 256;  N = 1024; noff = 0;   break;
    default: src = Wf2;    dst = t_f2; K = 1024; N = 256;  noff = 0;   break;
  }
  const int tilesK = K >> 5;
  const int nt = tilesK * (N >> 5);
  if ((int)blockIdx.x >= nt) return;
  const int tk = blockIdx.x % tilesK, tn = blockIdx.x / tilesK;
  const int k0 = tk * 32, n0 = tn * 32;
  const int t = threadIdx.x;
  const int r = t >> 3, c4 = (t & 7) * 4;
  float4 v = make_float4(0.f, 0.f, 0.f, 0.f);
  if (src) v = *(const float4*)(src + (size_t)(k0 + r) * N + n0 + c4);
  tile[r][c4] = v.x; tile[r][c4 + 1] = v.y; tile[r][c4 + 2] = v.z; tile[r][c4 + 3] = v.w;
  __syncthreads();
  const int nn = t >> 3, kc = (t & 7) * 4;
  s16x4 o;
  o.x = f2b(tile[kc][nn]); o.y = f2b(tile[kc + 1][nn]);
  o.z = f2b(tile[kc + 2][nn]); o.w = f2b(tile[kc + 3][nn]);
  *(s16x4*)(dst + (size_t)(noff + n0 + nn) * K + k0 + kc) = o;
}

// ---------------------------------------------------------------------------
// value fp32 [12600x256] -> bf16 [12672x256] (zero-padded rows)
// ---------------------------------------------------------------------------
__global__ __launch_bounds__(256) void vconvert(const float* __restrict__ x,
                                                short* __restrict__ y)
{
  const int i = (blockIdx.x * 256 + threadIdx.x) * 4;
  if (i >= 12672 * 256) return;
  s16x4 o = (s16x4){0, 0, 0, 0};
  if (i < 12600 * 256) {
    float4 v = *(const float4*)(x + i);
    o.x = f2b(v.x); o.y = f2b(v.y); o.z = f2b(v.z); o.w = f2b(v.w);
  }
  *(s16x4*)(y + i) = o;
}

// ---------------------------------------------------------------------------
// LayerNorm: one wave per row of 256.
// ---------------------------------------------------------------------------
__global__ __launch_bounds__(256) void ln_kernel(
    const float* __restrict__ x, const float* __restrict__ pos,
    const float* __restrict__ g, const float* __restrict__ bta,
    float* __restrict__ yf, short* __restrict__ ybf)
{
  const int row  = blockIdx.x * 4 + (threadIdx.x >> 6);
  const int lane = threadIdx.x & 63;
  const float4 v = ((const float4*)(x + (size_t)row * 256))[lane];
  float s = v.x + v.y + v.z + v.w;
#pragma unroll
  for (int o = 32; o; o >>= 1) s += __shfl_xor(s, o);
  const float mean = s * (1.f / 256.f);
  const float dx = v.x - mean, dy = v.y - mean, dz = v.z - mean, dw = v.w - mean;
  float s2 = dx * dx + dy * dy + dz * dz + dw * dw;
#pragma unroll
  for (int o = 32; o; o >>= 1) s2 += __shfl_xor(s2, o);
  const float inv = rsqrtf(s2 * (1.f / 256.f) + 1e-5f);
  const float4 gv = ((const float4*)g)[lane];
  const float4 bv = ((const float4*)bta)[lane];
  float4 o1 = make_float4(dx * inv * gv.x + bv.x, dy * inv * gv.y + bv.y,
                          dz * inv * gv.z + bv.z, dw * inv * gv.w + bv.w);
  if (yf) ((float4*)(yf + (size_t)row * 256))[lane] = o1;
  if (ybf) {
    if (pos) {
      const float4 pv = ((const float4*)(pos + (size_t)row * 256))[lane];
      o1.x += pv.x; o1.y += pv.y; o1.z += pv.z; o1.w += pv.w;
    }
    s16x4 ob; ob.x = f2b(o1.x); ob.y = f2b(o1.y); ob.z = f2b(o1.z); ob.w = f2b(o1.w);
    ((s16x4*)(ybf + (size_t)row * 256))[lane] = ob;
  }
}

// ---------------------------------------------------------------------------
// bf16 MFMA GEMM: 128x128 tile, BK=64, single-buffer two-barrier K-loop,
// 8-chunk rotation swizzle (bank = pos only -> conflict-free), swapped MFMA,
// LDS-staged epilogue (full-line coalesced stores + coalesced residuals).
// EPI: 1=gelu->bf16 | 2=f32+bias+add1+add2 | 3=f32+bias+add1
//      4=oa (bias split 192/96, f32) | 5=bf16+bias
// ---------------------------------------------------------------------------
template <int EPI>
__global__ __launch_bounds__(256) void gemm_bf16(
    const short* __restrict__ A, const short* __restrict__ Bt,
    const float* __restrict__ bias, const float* __restrict__ bias2,
    const float* __restrict__ add1, const float* __restrict__ add2,
    void* __restrict__ Cout, int M, int Nreal, int ldc, int K)
{
  __shared__ __align__(16) char smem[32768];
  short* sA = (short*)smem;       // [128][64] shorts, pos-swizzled
  short* sB = sA + 8192;          // [128][64]
  float* sf = (float*)smem;       // epilogue staging [32][132]

  const int t = threadIdx.x;
  const int wave = t >> 6, lane = t & 63;
  const int quad = lane >> 4, l16 = lane & 15;
  const int wm = (wave & 1) * 64, wn = (wave >> 1) * 64;
  const int m0 = blockIdx.y * 128, n0 = blockIdx.x * 128;

  f32x4 acc[4][4];
#pragma unroll
  for (int i = 0; i < 4; i++)
#pragma unroll
    for (int j = 0; j < 4; j++) acc[i][j] = (f32x4){0.f, 0.f, 0.f, 0.f};

  // Staging: lane L: srow=L>>3 (0..7), pos=L&7; stages global k-chunk
  // (pos+srow)&7 at LDS position pos of its row (glds dest = base + L*16B).
  const int srow = lane >> 3, pos = lane & 7;
  const int chunk = (pos + srow) & 7;
  const short* gA = A + (size_t)(m0 + wave * 32 + srow) * K + chunk * 8;
  const short* gB = Bt + (size_t)(n0 + wave * 32 + srow) * K + chunk * 8;

  const int nk = K >> 6;
  for (int kt = 0; kt < nk; ++kt) {
    if (kt) __syncthreads();
    const int ko = kt * 64;
#pragma unroll
    for (int g = 0; g < 4; ++g) {
      glds16(gA + ko + (size_t)(g * 8) * K, sA + (wave * 32 + g * 8) * 64);
      glds16(gB + ko + (size_t)(g * 8) * K, sB + (wave * 32 + g * 8) * 64);
    }
    __syncthreads();
#pragma unroll
    for (int kk = 0; kk < 2; ++kk) {
      short8 af[4], bf[4];
      const int c = kk * 4 + quad;
#pragma unroll
      for (int i = 0; i < 4; i++) {
        const int lrA = wm + i * 16 + l16;
        af[i] = *(const short8*)&sA[lrA * 64 + ((c - lrA) & 7) * 8];
        const int lrB = wn + i * 16 + l16;
        bf[i] = *(const short8*)&sB[lrB * 64 + ((c - lrB) & 7) * 8];
      }
      // SWAPPED operands: l16 -> C row, quad*4+r -> C col
#pragma unroll
      for (int i = 0; i < 4; i++)
#pragma unroll
        for (int j = 0; j < 4; j++) acc[i][j] = mfma16(bf[j], af[i], acc[i][j]);
    }
  }
  __syncthreads();

  // Epilogue: 4 bands of 32 rows x 128 cols, staged raw in LDS then stored
  // with consecutive-lane addresses (full cachelines).
#pragma unroll
  for (int b = 0; b < 4; ++b) {
    const bool mine = (b < 2) ? (wm == 0) : (wm == 64);
    if (mine) {
#pragma unroll
      for (int ii = 0; ii < 2; ++ii) {
        const int i = (b & 1) * 2 + ii;
        const int rr = ii * 16 + l16;
#pragma unroll
        for (int j = 0; j < 4; ++j)
          *(f32x4*)&sf[rr * 132 + wn + quad * 4 + j * 16] = acc[i][j];
      }
    }
    __syncthreads();
#pragma unroll
    for (int r2 = 0; r2 < 4; ++r2) {
      const int fidx = r2 * 1024 + t * 4;
      const int row = fidx >> 7, col = fidx & 127;
      const int gm = m0 + b * 32 + row;
      const int cc = n0 + col;
      if (gm < M && cc < Nreal) {
        const float4 v = *(const float4*)&sf[row * 132 + col];
        float4 bb;
        if (EPI == 4) bb = (cc < 192) ? *(const float4*)(bias + cc)
                                      : *(const float4*)(bias2 + cc - 192);
        else bb = *(const float4*)(bias + cc);
        float v0 = v.x + bb.x, v1 = v.y + bb.y, v2 = v.z + bb.z, v3 = v.w + bb.w;
        if (EPI == 1) {
          v0 = gelu1(v0); v1 = gelu1(v1); v2 = gelu1(v2); v3 = gelu1(v3);
          s16x4 o; o.x = f2b(v0); o.y = f2b(v1); o.z = f2b(v2); o.w = f2b(v3);
          *(s16x4*)((short*)Cout + (size_t)gm * ldc + cc) = o;
        } else if (EPI == 5) {
          s16x4 o; o.x = f2b(v0); o.y = f2b(v1); o.z = f2b(v2); o.w = f2b(v3);
          *(s16x4*)((short*)Cout + (size_t)gm * ldc + cc) = o;
        } else {
          if (EPI == 2 || EPI == 3) {
            const float4 a1 = *(const float4*)(add1 + (size_t)gm * ldc + cc);
            v0 += a1.x; v1 += a1.y; v2 += a1.z; v3 += a1.w;
            if (EPI == 2) {
              const float4 a2 = *(const float4*)(add2 + (size_t)gm * ldc + cc);
              v0 += a2.x; v1 += a2.y; v2 += a2.z; v3 += a2.w;
            }
          }
          *(float4*)((float*)Cout + (size_t)gm * ldc + cc) =
              make_float4(v0, v1, v2, v3);
        }
      }
    }
    __syncthreads();
  }
}

// ---------------------------------------------------------------------------
// prep_points: one thread per (row, head). Fused softmax + bilinear setup.
// ---------------------------------------------------------------------------
__global__ __launch_bounds__(256) void prep_points(
    const float* __restrict__ oa, const float* __restrict__ refp,
    int4* __restrict__ tIdx, s16x4* __restrict__ tW)
{
  const int t = blockIdx.x * 256 + threadIdx.x;   // 131072 = 16384*8
  const int row = t >> 3, h = t & 7;
  const float* oarow = oa + (size_t)row * 288;

  float off[24];
  const float4* op = (const float4*)(oarow + h * 24);
#pragma unroll
  for (int i = 0; i < 6; i++) {
    const float4 v = op[i];
    off[i * 4] = v.x; off[i * 4 + 1] = v.y; off[i * 4 + 2] = v.z; off[i * 4 + 3] = v.w;
  }
  float lg[12];
  const float4* ap = (const float4*)(oarow + 192 + h * 12);
#pragma unroll
  for (int i = 0; i < 3; i++) {
    const float4 v = ap[i];
    lg[i * 4] = v.x; lg[i * 4 + 1] = v.y; lg[i * 4 + 2] = v.z; lg[i * 4 + 3] = v.w;
  }
  const float* rp = refp + (size_t)row * 6;
  const float Rx[3] = {rp[0], rp[2], rp[4]}, Ry[3] = {rp[1], rp[3], rp[5]};

  float mx = lg[0];
#pragma unroll
  for (int i = 1; i < 12; i++) mx = fmaxf(mx, lg[i]);
  float sum = 0.f;
#pragma unroll
  for (int i = 0; i < 12; i++) { lg[i] = __expf(lg[i] - mx); sum += lg[i]; }
  const float inv = 1.f / sum;

  const int b = row >> 13;
  const int Hs[3] = {60, 30, 15}, Ws[3] = {80, 40, 20}, St[3] = {0, 4800, 6000};

  int4* ti = tIdx + (size_t)t * 12;
  s16x4* tw = tW + (size_t)t * 12;
#pragma unroll
  for (int p = 0; p < 12; p++) {
    const int l = p >> 2;
    const int W = Ws[l], H = Hs[l];
    const float gx = Rx[l] * W + off[p * 2]     - 0.5f;
    const float gy = Ry[l] * H + off[p * 2 + 1] - 0.5f;
    const float x0f = floorf(gx), y0f = floorf(gy);
    const float wx = gx - x0f, wy = gy - y0f;
    const int x0 = (int)x0f, y0 = (int)y0f;
    const float aw = lg[p] * inv;
    float cw[4] = {(1.f - wx) * (1.f - wy), wx * (1.f - wy),
                   (1.f - wx) * wy, wx * wy};
    const int base = b * 6300 + St[l];
    int ci[4];
#pragma unroll
    for (int k = 0; k < 4; k++) {
      const int xx = x0 + (k & 1), yy = y0 + (k >> 1);
      const bool valid = (xx >= 0) & (xx < W) & (yy >= 0) & (yy < H);
      const int xc = min(max(xx, 0), W - 1);
      const int yc = min(max(yy, 0), H - 1);
      ci[k] = ((base + yc * W + xc) << 8) + h * 32;
      cw[k] = valid ? cw[k] * aw : 0.f;
    }
    ti[p] = make_int4(ci[0], ci[1], ci[2], ci[3]);
    s16x4 wv; wv.x = f2b(cw[0]); wv.y = f2b(cw[1]); wv.z = f2b(cw[2]); wv.w = f2b(cw[3]);
    tw[p] = wv;
  }
}

// ---------------------------------------------------------------------------
// deform_gather: thread = (row, h, c4); c4 covers 8 channels via 16 B loads.
// ---------------------------------------------------------------------------
__global__ __launch_bounds__(256) void deform_gather(
    const short* __restrict__ vproj, const int4* __restrict__ tIdx,
    const s16x4* __restrict__ tW, short* __restrict__ out)
{
  const int t = blockIdx.x * 256 + threadIdx.x;  // 524288 = 16384*8*4
  const int unit = t >> 2, c4 = (t & 3) * 8;
  const int4* ip = tIdx + (size_t)unit * 12;
  const s16x4* wp = tW + (size_t)unit * 12;
  float acc[8];
#pragma unroll
  for (int i = 0; i < 8; i++) acc[i] = 0.f;

#pragma unroll 2
  for (int p = 0; p < 12; p++) {
    const int4 idx = ip[p];
    const s16x4 wb = wp[p];
    const float w0 = b2f(wb.x), w1 = b2f(wb.y), w2 = b2f(wb.z), w3 = b2f(wb.w);
    const short8 v0 = *(const short8*)(vproj + idx.x + c4);
    const short8 v1 = *(const short8*)(vproj + idx.y + c4);
    const short8 v2 = *(const short8*)(vproj + idx.z + c4);
    const short8 v3 = *(const short8*)(vproj + idx.w + c4);
    float f0[8], f1[8], f2[8], f3[8];
    b8f(v0, f0); b8f(v1, f1); b8f(v2, f2); b8f(v3, f3);
#pragma unroll
    for (int j = 0; j < 8; j++)
      acc[j] += w0 * f0[j] + w1 * f1[j] + w2 * f2[j] + w3 * f3[j];
  }
  short8 o;
#pragma unroll
  for (int j = 0; j < 8; j++) o[j] = f2b(acc[j]);
  *(short8*)(out + (size_t)t * 8) = o;
}

// ---------------------------------------------------------------------------
// Launch
// ---------------------------------------------------------------------------
extern "C" void kernel_launch(void* const* d_in, const int* in_sizes, int n_in,
                              void* d_out, int out_size, void* d_ws, size_t ws_size,
                              hipStream_t stream)
{
  const float* query     = (const float*)d_in[0];
  const float* value     = (const float*)d_in[1];
  const float* query_pos = (const float*)d_in[2];
  const float* ref_pts   = (const float*)d_in[3];
  const float* g1  = (const float*)d_in[6];
  const float* b1  = (const float*)d_in[7];
  const float* Wo  = (const float*)d_in[8];
  const float* bo  = (const float*)d_in[9];
  const float* Wa  = (const float*)d_in[10];
  const float* ba  = (const float*)d_in[11];
  const float* Wv  = (const float*)d_in[12];
  const float* bv  = (const float*)d_in[13];
  const float* Wp  = (const float*)d_in[14];
  const float* bp  = (const float*)d_in[15];
  const float* g2  = (const float*)d_in[16];
  const float* b2  = (const float*)d_in[17];
  const float* Wf1 = (const float*)d_in[18];
  const float* bf1 = (const float*)d_in[19];
  const float* Wf2 = (const float*)d_in[20];
  const float* bf2 = (const float*)d_in[21];

  char* ws = (char*)d_ws;
  short* wt_oa   = (short*)(ws + 0);
  short* wt_v    = (short*)(ws + 196608);
  short* wt_p    = (short*)(ws + 327680);
  short* wt_f1   = (short*)(ws + 458752);
  short* wt_f2   = (short*)(ws + 983040);
  float* qn      = (float*)(ws + 1507328);    // 16384x256 f32
  short* qa      = (short*)(ws + 18284544);   // 16384x256 bf16 (later q2)
  float* oabuf   = (float*)(ws + 26673152);   // 16384x288 f32 (dead after prep)
  short* vproj   = (short*)(ws + 45547520);   // 12600x256 bf16
  short* sampled = (short*)(ws + 51998720);   // 16384x256 bf16
  float* qbuf    = (float*)(ws + 60387328);   // 16384x256 f32 (after tables die)
  short* valbf   = (short*)(ws + 77164544);   // 12672x256 bf16
  int4*  tIdx    = (int4*)(ws + 60387328);    // overlaps qbuf+valbf
  s16x4* tW      = (s16x4*)(ws + 85553152);   // end 98,136,064
  short* q2      = qa;
  short* hidden  = (short*)(ws + 26673152);   // 16384x1024 bf16
  float* outp = (float*)d_out;

  wconvert<<<dim3(256, 7), 256, 0, stream>>>(Wo, Wa, Wv, Wp, Wf1, Wf2,
                                             wt_oa, wt_v, wt_p, wt_f1, wt_f2);
  vconvert<<<3169, 256, 0, stream>>>(value, valbf);
  ln_kernel<<<4096, 256, 0, stream>>>(query, query_pos, g1, b1, qn, qa);
  // oa = qa @ [Wo|Wa] + [bo|ba]   [16384 x 288] f32 (raw logits)
  gemm_bf16<4><<<dim3(3, 128), 256, 0, stream>>>(qa, wt_oa, bo, ba, nullptr,
                                                 nullptr, oabuf, 16384, 288, 288, 256);
  // vproj = value @ Wv + bv -> bf16   [12600 x 256]
  gemm_bf16<5><<<dim3(2, 99), 256, 0, stream>>>(valbf, wt_v, bv, nullptr, nullptr,
                                                nullptr, vproj, 12600, 256, 256, 256);
  prep_points<<<512, 256, 0, stream>>>(oabuf, ref_pts, tIdx, tW);
  deform_gather<<<2048, 256, 0, stream>>>(vproj, tIdx, tW, sampled);
  // qbuf = sampled @ Wp + bp + qn + query   f32
  gemm_bf16<2><<<dim3(2, 128), 256, 0, stream>>>(sampled, wt_p, bp, nullptr, qn,
                                                 (const float*)query, qbuf,
                                                 16384, 256, 256, 256);
  ln_kernel<<<4096, 256, 0, stream>>>(qbuf, nullptr, g2, b2, nullptr, q2);
  // hidden = gelu(q2 @ Wf1 + bf1) bf16   [16384 x 1024]
  gemm_bf16<1><<<dim3(8, 128), 256, 0, stream>>>(q2, wt_f1, bf1, nullptr, nullptr,
                                                 nullptr, hidden, 16384, 1024, 1024, 256);
  // out = qbuf + hidden @ Wf2 + bf2   f32
  gemm_bf16<3><<<dim3(2, 128), 256, 0, stream>>>(hidden, wt_f2, bf2, nullptr, qbuf,
                                                 nullptr, outp, 16384, 256, 256, 1024);
}